// Round 2
// 376.986 us; speedup vs baseline: 1.0868x; 1.0868x over previous
//
#include <hip/hip_runtime.h>

#define MM 2048     // memory slots
#define BB 64       // batch
#define TT 4        // tokens per slot
#define DD 128      // embed dim
#define VV 50000    // vocab
#define VPAD 50176  // VV rounded up to multiple of 256
#define NPART 392   // gemm_o partial slots (one per block)

typedef float f4v __attribute__((ext_vector_type(4)));
typedef short s8v __attribute__((ext_vector_type(8)));

// float -> bf16 bits (RNE)
__device__ __forceinline__ unsigned short f2bf(float f) {
    unsigned int u = __float_as_uint(f);
    u = u + 0x7FFFu + ((u >> 16) & 1u);
    return (unsigned short)(u >> 16);
}

// ---- init: zero u (8192 f) and W (VPAD*BB f) — contiguous in workspace ----
__global__ void k_init(float4* __restrict__ p) {
    p[blockIdx.x * 256 + threadIdx.x] = make_float4(0.f, 0.f, 0.f, 0.f);
}

// ---- GEMM1 (MFMA bf16): P[v][b] = dot(C[h][v][:], u[b][:]) ----
// Block: 64 v-rows, all 64 b, K=128. LDS rows[128][136] bf16:
// rows 0..63 = C tile (A operand, [m][k]), rows 64..127 = u (BT, [n][k]).
// Wave w: v-rows 16w..16w+15; 4 k-steps x 4 b-tiles of 16x16x32 MFMA.
__global__ __launch_bounds__(256, 4) void k_gemm_p(const float* __restrict__ Ch,
                                                   const float* __restrict__ u,
                                                   float* __restrict__ P) {
    __shared__ short lds[128 * 136];  // 34.8 KB bf16
    const int t = threadIdx.x;
    const int v0 = blockIdx.x * 64;

    // stage: 128 rows x 128 floats -> bf16. coalesced float4 loads.
#pragma unroll
    for (int i = 0; i < 16; ++i) {
        const int G = i * 256 + t;        // f4-index
        const int row = G >> 5;           // 0..127
        const int c4 = G & 31;            // f4 within row
        float4 val;
        if (row < 64) {
            const int v = v0 + row;
            val = (v < VV) ? *(const float4*)(Ch + (size_t)v * DD + c4 * 4)
                           : make_float4(0.f, 0.f, 0.f, 0.f);
        } else {
            val = *(const float4*)(u + (size_t)(row - 64) * DD + c4 * 4);
        }
        const unsigned int lo = ((unsigned int)f2bf(val.y) << 16) | f2bf(val.x);
        const unsigned int hi = ((unsigned int)f2bf(val.w) << 16) | f2bf(val.z);
        *(uint2*)(lds + row * 136 + c4 * 4) = make_uint2(lo, hi);
    }
    __syncthreads();

    const int l = t & 63;
    const int w = t >> 6;       // wave id 0..3
    const int quad = l >> 4;    // 0..3
    const int n16 = l & 15;

    const int arow = (16 * w + n16) * 136;
    const int brow0 = (64 + 0 * 16 + n16) * 136;
    const int brow1 = (64 + 1 * 16 + n16) * 136;
    const int brow2 = (64 + 2 * 16 + n16) * 136;
    const int brow3 = (64 + 3 * 16 + n16) * 136;

    f4v ac0 = {0.f, 0.f, 0.f, 0.f}, ac1 = ac0, ac2 = ac0, ac3 = ac0;

#pragma unroll
    for (int s = 0; s < 4; ++s) {
        const int ko = s * 32 + quad * 8;
        const s8v av = *(const s8v*)(lds + arow + ko);
        const s8v b0 = *(const s8v*)(lds + brow0 + ko);
        const s8v b1 = *(const s8v*)(lds + brow1 + ko);
        const s8v b2 = *(const s8v*)(lds + brow2 + ko);
        const s8v b3 = *(const s8v*)(lds + brow3 + ko);
        ac0 = __builtin_amdgcn_mfma_f32_16x16x32_bf16(av, b0, ac0, 0, 0, 0);
        ac1 = __builtin_amdgcn_mfma_f32_16x16x32_bf16(av, b1, ac1, 0, 0, 0);
        ac2 = __builtin_amdgcn_mfma_f32_16x16x32_bf16(av, b2, ac2, 0, 0, 0);
        ac3 = __builtin_amdgcn_mfma_f32_16x16x32_bf16(av, b3, ac3, 0, 0, 0);
    }

    // D layout: n = lane&15, m = quad*4 + reg
    const int vbase = v0 + 16 * w + quad * 4;
#pragma unroll
    for (int r = 0; r < 4; ++r) {
        float* __restrict__ Pr = P + (size_t)(vbase + r) * 64 + n16;
        Pr[0]  = ac0[r];
        Pr[16] = ac1[r];
        Pr[32] = ac2[r];
        Pr[48] = ac3[r];
    }
}

// ---- fused attention: gather P -> softmax over m -> scatter into W ----
// One block per batch column b (64 blocks x 512 thr, 4 m-slots per thread).
// Tokens stay in registers between gather and scatter; s buffer eliminated.
__global__ __launch_bounds__(512) void k_attn(const int* __restrict__ st,
                                              const float* __restrict__ P,
                                              float* __restrict__ W) {
    const int b = blockIdx.x;
    const int tid = threadIdx.x;  // 0..511
    __shared__ float redmax[8];
    __shared__ float redsum[8];

    // token loads (independent, issued up-front)
    const int4 tk0 = *(const int4*)(st + ((size_t)(tid + 0)    * 64 + b) * 4);
    const int4 tk1 = *(const int4*)(st + ((size_t)(tid + 512)  * 64 + b) * 4);
    const int4 tk2 = *(const int4*)(st + ((size_t)(tid + 1024) * 64 + b) * 4);
    const int4 tk3 = *(const int4*)(st + ((size_t)(tid + 1536) * 64 + b) * 4);

    float v0 = 0.f, v1 = 0.f, v2 = 0.f, v3 = 0.f;
    if (tk0.x) v0 += P[(size_t)tk0.x * 64 + b];
    if (tk0.y) v0 += P[(size_t)tk0.y * 64 + b];
    if (tk0.z) v0 += P[(size_t)tk0.z * 64 + b];
    if (tk0.w) v0 += P[(size_t)tk0.w * 64 + b];
    if (tk1.x) v1 += P[(size_t)tk1.x * 64 + b];
    if (tk1.y) v1 += P[(size_t)tk1.y * 64 + b];
    if (tk1.z) v1 += P[(size_t)tk1.z * 64 + b];
    if (tk1.w) v1 += P[(size_t)tk1.w * 64 + b];
    if (tk2.x) v2 += P[(size_t)tk2.x * 64 + b];
    if (tk2.y) v2 += P[(size_t)tk2.y * 64 + b];
    if (tk2.z) v2 += P[(size_t)tk2.z * 64 + b];
    if (tk2.w) v2 += P[(size_t)tk2.w * 64 + b];
    if (tk3.x) v3 += P[(size_t)tk3.x * 64 + b];
    if (tk3.y) v3 += P[(size_t)tk3.y * 64 + b];
    if (tk3.z) v3 += P[(size_t)tk3.z * 64 + b];
    if (tk3.w) v3 += P[(size_t)tk3.w * 64 + b];

    // block max
    float mx = fmaxf(fmaxf(v0, v1), fmaxf(v2, v3));
#pragma unroll
    for (int off = 32; off; off >>= 1) mx = fmaxf(mx, __shfl_xor(mx, off, 64));
    if ((tid & 63) == 0) redmax[tid >> 6] = mx;
    __syncthreads();
    float gmax = redmax[0];
#pragma unroll
    for (int i = 1; i < 8; ++i) gmax = fmaxf(gmax, redmax[i]);

    v0 = __expf(v0 - gmax); v1 = __expf(v1 - gmax);
    v2 = __expf(v2 - gmax); v3 = __expf(v3 - gmax);
    float sum = (v0 + v1) + (v2 + v3);
#pragma unroll
    for (int off = 32; off; off >>= 1) sum += __shfl_xor(sum, off, 64);
    if ((tid & 63) == 0) redsum[tid >> 6] = sum;
    __syncthreads();
    float tot = redsum[0];
#pragma unroll
    for (int i = 1; i < 8; ++i) tot += redsum[i];
    const float inv = 1.f / tot;

    v0 *= inv; v1 *= inv; v2 *= inv; v3 *= inv;

    // scatter (atomics only collide within this block: b is exclusive)
    if (tk0.x) atomicAdd(W + (size_t)tk0.x * 64 + b, v0);
    if (tk0.y) atomicAdd(W + (size_t)tk0.y * 64 + b, v0);
    if (tk0.z) atomicAdd(W + (size_t)tk0.z * 64 + b, v0);
    if (tk0.w) atomicAdd(W + (size_t)tk0.w * 64 + b, v0);
    if (tk1.x) atomicAdd(W + (size_t)tk1.x * 64 + b, v1);
    if (tk1.y) atomicAdd(W + (size_t)tk1.y * 64 + b, v1);
    if (tk1.z) atomicAdd(W + (size_t)tk1.z * 64 + b, v1);
    if (tk1.w) atomicAdd(W + (size_t)tk1.w * 64 + b, v1);
    if (tk2.x) atomicAdd(W + (size_t)tk2.x * 64 + b, v2);
    if (tk2.y) atomicAdd(W + (size_t)tk2.y * 64 + b, v2);
    if (tk2.z) atomicAdd(W + (size_t)tk2.z * 64 + b, v2);
    if (tk2.w) atomicAdd(W + (size_t)tk2.w * 64 + b, v2);
    if (tk3.x) atomicAdd(W + (size_t)tk3.x * 64 + b, v3);
    if (tk3.y) atomicAdd(W + (size_t)tk3.y * 64 + b, v3);
    if (tk3.z) atomicAdd(W + (size_t)tk3.z * 64 + b, v3);
    if (tk3.w) atomicAdd(W + (size_t)tk3.w * 64 + b, v3);
}

// ---- GEMM2 (fp32 tiled): upart[block] = sum_v W[v][b] * C2[v][d], 128-v slice ----
// Block 256 thr, 2 k-groups (waves 0,1 = kk 0..31; waves 2,3 = kk 32..63).
// (a) each thread zero-writes-back the W float4 it staged (rezero flag)
//     -> k_zero_w launches eliminated; (b) the two k-groups are combined via
//     LDS so each block writes ONE partial -> up traffic halved (392 slots).
__global__ __launch_bounds__(256, 3) void k_gemm_o(const float* __restrict__ C2,
                                                   float* __restrict__ W,
                                                   float* __restrict__ upart,
                                                   const int rezero) {
    __shared__ float Wl[64 * 68];    // 17.4 KB
    __shared__ float Cl[64 * 136];   // 34.8 KB (reused for k-group combine)
    const int t = threadIdx.x;
    const int g = t >> 7;            // k-group
    const int b0 = ((t >> 4) & 7) * 8;
    const int d0 = (t & 15) * 8;
    const int vb = blockIdx.x * 128;

    f4v a0l = {0.f, 0.f, 0.f, 0.f}, a0h = a0l, a1l = a0l, a1h = a0l;
    f4v a2l = a0l, a2h = a0l, a3l = a0l, a3h = a0l;
    f4v a4l = a0l, a4h = a0l, a5l = a0l, a5h = a0l;
    f4v a6l = a0l, a6h = a0l, a7l = a0l, a7h = a0l;

    for (int cc = 0; cc < 2; ++cc) {
        const int vc = vb + cc * 64;
        // stage W chunk: 64 rows x 64 f; zero-writeback keeps W clean for
        // next hop's scatter (same thread, same address -> program order).
#pragma unroll
        for (int i = 0; i < 4; ++i) {
            const int G = i * 256 + t;
            const int row = G >> 4, c4 = G & 15;
            float* wp = W + (size_t)(vc + row) * 64 + c4 * 4;
            const float4 val = *(const float4*)wp;
            *(float4*)&Wl[row * 68 + c4 * 4] = val;
            if (rezero) *(float4*)wp = make_float4(0.f, 0.f, 0.f, 0.f);
        }
        // stage C2 chunk: 64 rows x 128 f (guard v < VV)
#pragma unroll
        for (int i = 0; i < 8; ++i) {
            const int G = i * 256 + t;
            const int row = G >> 5, c4 = G & 31;
            const int v = vc + row;
            float4 val = (v < VV) ? *(const float4*)(C2 + (size_t)v * DD + c4 * 4)
                                  : make_float4(0.f, 0.f, 0.f, 0.f);
            *(float4*)&Cl[row * 136 + c4 * 4] = val;
        }
        __syncthreads();

#define FMA_ROW(al, ah, wc)            \
    al += wc * cA; ah += wc * cB;

#pragma unroll
        for (int j = 0; j < 32; ++j) {
            const int kk = g * 32 + j;
            const f4v wA = *(const f4v*)&Wl[kk * 68 + b0];
            const f4v wB = *(const f4v*)&Wl[kk * 68 + b0 + 4];
            const f4v cA = *(const f4v*)&Cl[kk * 136 + d0];
            const f4v cB = *(const f4v*)&Cl[kk * 136 + d0 + 4];
            FMA_ROW(a0l, a0h, wA[0]) FMA_ROW(a1l, a1h, wA[1])
            FMA_ROW(a2l, a2h, wA[2]) FMA_ROW(a3l, a3h, wA[3])
            FMA_ROW(a4l, a4h, wB[0]) FMA_ROW(a5l, a5h, wB[1])
            FMA_ROW(a6l, a6h, wB[2]) FMA_ROW(a7l, a7h, wB[3])
        }
#undef FMA_ROW
        __syncthreads();
    }

    // combine k-groups in LDS (Cl reused): g1 stores, g0 adds + writes partial
    if (g == 1) {
#define STL(i, al, ah)                                   \
        *(f4v*)&Cl[(b0 + i) * 136 + d0] = al;            \
        *(f4v*)&Cl[(b0 + i) * 136 + d0 + 4] = ah;
        STL(0, a0l, a0h) STL(1, a1l, a1h) STL(2, a2l, a2h) STL(3, a3l, a3h)
        STL(4, a4l, a4h) STL(5, a5l, a5h) STL(6, a6l, a6h) STL(7, a7l, a7h)
#undef STL
    }
    __syncthreads();
    if (g == 0) {
        float* __restrict__ up = upart + (size_t)blockIdx.x * (BB * DD);
#define STG(i, al, ah) {                                             \
        const f4v xl = al + *(const f4v*)&Cl[(b0 + i) * 136 + d0];   \
        const f4v xh = ah + *(const f4v*)&Cl[(b0 + i) * 136 + d0 + 4]; \
        *(f4v*)(up + (b0 + i) * DD + d0) = xl;                       \
        *(f4v*)(up + (b0 + i) * DD + d0 + 4) = xh; }
        STG(0, a0l, a0h) STG(1, a1l, a1h) STG(2, a2l, a2h) STG(3, a3l, a3h)
        STG(4, a4l, a4h) STG(5, a5l, a5h) STG(6, a6l, a6h) STG(7, a7l, a7h)
#undef STG
    }
}

// ---- reduce upart over 392 slots into u (8 k-chunks x 49 slots) ----
__global__ __launch_bounds__(256) void k_reduce_u(const float* __restrict__ up,
                                                  float* __restrict__ u) {
    const int jc = blockIdx.x & 31;   // 32 j-chunks of 256
    const int kc = blockIdx.x >> 5;   // 8 k-chunks of 49
    const int j = jc * 256 + threadIdx.x;
    const float* __restrict__ p = up + (size_t)kc * 49 * (BB * DD) + j;
    float s = 0.f;
#pragma unroll 7
    for (int k = 0; k < 49; ++k) s += p[(size_t)k * (BB * DD)];
    atomicAdd(u + j, s);
}

// ---- copy u -> out ----
__global__ void k_copy(const float* __restrict__ u, float* __restrict__ out) {
    const int i = blockIdx.x * 256 + threadIdx.x;
    out[i] = u[i];
}

extern "C" void kernel_launch(void* const* d_in, const int* in_sizes, int n_in,
                              void* d_out, int out_size, void* d_ws, size_t ws_size,
                              hipStream_t stream) {
    const int* st = (const int*)d_in[0];
    const float* C = (const float*)d_in[1];

    // workspace layout (u and W contiguous so k_init zeroes both):
    float* u  = (float*)d_ws;                 // 8192 f, [b][d]
    float* W  = u + BB * DD;                  // VPAD*64 f (scatter target)
    float* P  = W + (size_t)VPAD * BB;        // VPAD*64 f (GEMM1 output)
    float* up = P + (size_t)VPAD * BB;        // 392*8192 f partials

    // zero u + W once; W self-cleans each hop via gemm_o writeback
    k_init<<<(BB * DD + VPAD * BB) / 1024, 256, 0, stream>>>((float4*)u);

    for (int hop = 0; hop < 3; ++hop) {
        const float* Ch  = C + (size_t)hop * VV * DD;
        const float* Ch1 = C + (size_t)(hop + 1) * VV * DD;

        k_gemm_p<<<VPAD / 64, 256, 0, stream>>>(Ch, u, P);        // 784 blocks
        k_attn<<<BB, 512, 0, stream>>>(st, P, W);                 // 64 blocks
        k_gemm_o<<<VPAD / 128, 256, 0, stream>>>(Ch1, W, up,
                                                 hop < 2 ? 1 : 0); // 392 blocks
        k_reduce_u<<<256, 256, 0, stream>>>(up, u);               // 256 blocks
    }

    k_copy<<<(BB * DD) / 256, 256, 0, stream>>>(u, (float*)d_out);
}